// Round 1
// baseline (1638.658 us; speedup 1.0000x reference)
//
#include <hip/hip_runtime.h>

#define Bc 4
#define Cc 64
#define Nc 8192
#define Kc 40
#define CN (Cc * Nc)   // 524288

// ---------------------------------------------------------------- aa kernel
__global__ __launch_bounds__(256) void aa_kernel(const float* __restrict__ x,
                                                 float* __restrict__ aa) {
  const int e = blockIdx.x * 256 + threadIdx.x;  // 0..32767
  const int b = e >> 13, n = e & 8191;
  const float* xb = x + (size_t)b * CN + n;
  float s = 0.f;
#pragma unroll
  for (int c = 0; c < 64; ++c) {
    const float v = xb[c * Nc];
    s = fmaf(v, v, s);
  }
  aa[e] = s;
}

// ---------------------------------------------------------------- projection
// qp/kp/vp[b][n][o] = sum_c W[o][c] * x[b][c][n]
__global__ __launch_bounds__(256) void proj_kernel(
    const float* __restrict__ x, const float* __restrict__ Wq,
    const float* __restrict__ Wk, const float* __restrict__ Wv,
    float* __restrict__ qp, float* __restrict__ kp, float* __restrict__ vp) {
  __shared__ float xs[64 * 64];  // [c][p]
  __shared__ float wt[64 * 64];  // [c][o]
  const int t = threadIdx.x;
  const int w = t >> 6, lane = t & 63;
  const int b = blockIdx.x >> 7;
  const int n0 = (blockIdx.x & 127) << 6;
  const float* xb = x + (size_t)b * CN;
  for (int c = w; c < 64; c += 4) xs[c * 64 + lane] = xb[c * Nc + n0 + lane];

  const float* Ws[3] = {Wq, Wk, Wv};
  float* Ds[3] = {qp, kp, vp};
  for (int mtx = 0; mtx < 3; ++mtx) {
    __syncthreads();
    const float* W = Ws[mtx];
    for (int q = t; q < 4096; q += 256) {
      const int o = q & 63, c = q >> 6;
      wt[c * 64 + o] = W[o * 64 + c];
    }
    __syncthreads();
    float acc[16];
#pragma unroll
    for (int k = 0; k < 16; ++k) acc[k] = 0.f;
#pragma unroll 8
    for (int c = 0; c < 64; ++c) {
      const float xv = xs[c * 64 + lane];
      const float4 w0 = *(const float4*)&wt[c * 64 + w * 16 + 0];
      const float4 w1 = *(const float4*)&wt[c * 64 + w * 16 + 4];
      const float4 w2 = *(const float4*)&wt[c * 64 + w * 16 + 8];
      const float4 w3 = *(const float4*)&wt[c * 64 + w * 16 + 12];
      acc[0] = fmaf(xv, w0.x, acc[0]);   acc[1] = fmaf(xv, w0.y, acc[1]);
      acc[2] = fmaf(xv, w0.z, acc[2]);   acc[3] = fmaf(xv, w0.w, acc[3]);
      acc[4] = fmaf(xv, w1.x, acc[4]);   acc[5] = fmaf(xv, w1.y, acc[5]);
      acc[6] = fmaf(xv, w1.z, acc[6]);   acc[7] = fmaf(xv, w1.w, acc[7]);
      acc[8] = fmaf(xv, w2.x, acc[8]);   acc[9] = fmaf(xv, w2.y, acc[9]);
      acc[10] = fmaf(xv, w2.z, acc[10]); acc[11] = fmaf(xv, w2.w, acc[11]);
      acc[12] = fmaf(xv, w3.x, acc[12]); acc[13] = fmaf(xv, w3.y, acc[13]);
      acc[14] = fmaf(xv, w3.z, acc[14]); acc[15] = fmaf(xv, w3.w, acc[15]);
    }
    float* dst = Ds[mtx] + ((size_t)(b * Nc + n0 + lane)) * 64 + w * 16;
    *(float4*)(dst + 0) = make_float4(acc[0], acc[1], acc[2], acc[3]);
    *(float4*)(dst + 4) = make_float4(acc[4], acc[5], acc[6], acc[7]);
    *(float4*)(dst + 8) = make_float4(acc[8], acc[9], acc[10], acc[11]);
    *(float4*)(dst + 12) = make_float4(acc[12], acc[13], acc[14], acc[15]);
  }
}

// ---------------------------------------------------------------- KNN top-40
// pd = 2*inner - aa_i - aa_j ; keep 40 largest per row (set semantics).
__global__ __launch_bounds__(256) void knn_kernel(const float* __restrict__ x,
                                                  const float* __restrict__ aa,
                                                  int* __restrict__ knn) {
  __shared__ float rowT[64 * 64];         // [c][r]
  __shared__ float colT[64 * 64];         // [c][j]
  __shared__ float qv[64 * 64];           // per-row qualifier queue values
  __shared__ unsigned short qidx[64 * 64];// per-row qualifier queue col idx
  __shared__ int qcnt[64];
  __shared__ float thr[64];

  const int t = threadIdx.x;
  const int w = t >> 6;
  const int lane = t & 63;
  const int b = blockIdx.x >> 7;
  const int i0 = (blockIdx.x & 127) << 6;
  const float* xb = x + (size_t)b * CN;
  const float* aab = aa + b * Nc;

  for (int c = w; c < 64; c += 4) rowT[c * 64 + lane] = xb[c * Nc + i0 + lane];
  if (t < 64) { qcnt[t] = 0; thr[t] = -INFINITY; }

  const int tr = t >> 4;       // 0..15 -> rows tr*4..tr*4+3
  const int tc = t & 15;       // 0..15 -> cols tc*4..tc*4+3
  const float4 rA4 = *(const float4*)&aab[i0 + tr * 4];
  const float rA[4] = {rA4.x, rA4.y, rA4.z, rA4.w};

  // owner lane (wave 0 lane r) keeps the top-40 list for row r in registers
  float lv[40]; int li[40];
#pragma unroll
  for (int q2 = 0; q2 < 40; ++q2) { lv[q2] = -INFINITY; li[q2] = 0; }
  float lmin = -INFINITY; int lminpos = 0;

  __syncthreads();

  for (int jt = 0; jt < 128; ++jt) {
    const int j0 = jt << 6;

    // drain previous tile's queue (wave 0) while other waves stage colT
    if (w == 0) {
      const int r = lane;
      const int cnt = qcnt[r];
      for (int e2 = 0; e2 < cnt; ++e2) {
        const float v = qv[r * 64 + e2];
        if (v > lmin) {
          const int jj = (int)qidx[r * 64 + e2];
#pragma unroll
          for (int q2 = 0; q2 < 40; ++q2)
            if (q2 == lminpos) { lv[q2] = v; li[q2] = jj; }
          float nm = lv[0]; int np2 = 0;
#pragma unroll
          for (int q2 = 1; q2 < 40; ++q2) {
            const bool lt = lv[q2] < nm;
            nm = lt ? lv[q2] : nm;
            np2 = lt ? q2 : np2;
          }
          lmin = nm; lminpos = np2;
        }
      }
      qcnt[r] = 0;
      thr[r] = lmin;
    }
    for (int c = w; c < 64; c += 4) colT[c * 64 + lane] = xb[c * Nc + j0 + lane];
    __syncthreads();

    float acc[4][4];
#pragma unroll
    for (int i = 0; i < 4; ++i)
#pragma unroll
      for (int jj = 0; jj < 4; ++jj) acc[i][jj] = 0.f;

#pragma unroll 16
    for (int c = 0; c < 64; ++c) {
      const float4 av = *(const float4*)&rowT[c * 64 + tr * 4];
      const float4 bv = *(const float4*)&colT[c * 64 + tc * 4];
      acc[0][0] = fmaf(av.x, bv.x, acc[0][0]); acc[0][1] = fmaf(av.x, bv.y, acc[0][1]);
      acc[0][2] = fmaf(av.x, bv.z, acc[0][2]); acc[0][3] = fmaf(av.x, bv.w, acc[0][3]);
      acc[1][0] = fmaf(av.y, bv.x, acc[1][0]); acc[1][1] = fmaf(av.y, bv.y, acc[1][1]);
      acc[1][2] = fmaf(av.y, bv.z, acc[1][2]); acc[1][3] = fmaf(av.y, bv.w, acc[1][3]);
      acc[2][0] = fmaf(av.z, bv.x, acc[2][0]); acc[2][1] = fmaf(av.z, bv.y, acc[2][1]);
      acc[2][2] = fmaf(av.z, bv.z, acc[2][2]); acc[2][3] = fmaf(av.z, bv.w, acc[2][3]);
      acc[3][0] = fmaf(av.w, bv.x, acc[3][0]); acc[3][1] = fmaf(av.w, bv.y, acc[3][1]);
      acc[3][2] = fmaf(av.w, bv.z, acc[3][2]); acc[3][3] = fmaf(av.w, bv.w, acc[3][3]);
    }

    // filter: append qualifiers to per-row queues
    const float4 cA4 = *(const float4*)&aab[j0 + tc * 4];
    const float cA[4] = {cA4.x, cA4.y, cA4.z, cA4.w};
#pragma unroll
    for (int i = 0; i < 4; ++i) {
      const int r = tr * 4 + i;
      const float th = thr[r];
#pragma unroll
      for (int jj = 0; jj < 4; ++jj) {
        const float v = 2.0f * acc[i][jj] - rA[i] - cA[jj];
        if (v > th) {
          const int pos = atomicAdd(&qcnt[r], 1);
          qv[r * 64 + pos] = v;
          qidx[r * 64 + pos] = (unsigned short)(j0 + tc * 4 + jj);
        }
      }
    }
    __syncthreads();
  }

  // final drain + output
  if (w == 0) {
    const int r = lane;
    const int cnt = qcnt[r];
    for (int e2 = 0; e2 < cnt; ++e2) {
      const float v = qv[r * 64 + e2];
      if (v > lmin) {
        const int jj = (int)qidx[r * 64 + e2];
#pragma unroll
        for (int q2 = 0; q2 < 40; ++q2)
          if (q2 == lminpos) { lv[q2] = v; li[q2] = jj; }
        float nm = lv[0]; int np2 = 0;
#pragma unroll
        for (int q2 = 1; q2 < 40; ++q2) {
          const bool lt = lv[q2] < nm;
          nm = lt ? lv[q2] : nm;
          np2 = lt ? q2 : np2;
        }
        lmin = nm; lminpos = np2;
      }
    }
    int* dst = knn + (size_t)(b * Nc + i0 + r) * Kc;
#pragma unroll
    for (int q2 = 0; q2 < 40; ++q2) dst[q2] = li[q2];
  }
}

// ---------------------------------------------------------------- attention
// one wave per point; lane = channel; out = sum_j a_j*vp[j] - vp[n]; y = x + out
__global__ __launch_bounds__(256) void attn_kernel(
    const float* __restrict__ x, const float* __restrict__ qp,
    const float* __restrict__ kp, const float* __restrict__ vp,
    const int* __restrict__ knn, float* __restrict__ y) {
  const int lane = threadIdx.x & 63;
  const int wid = threadIdx.x >> 6;
  const int pt = (blockIdx.x << 2) + wid;  // 0..32767
  const int b = pt >> 13;
  const int nn = pt & 8191;
  const float q = qp[(size_t)pt * 64 + lane];
  const float vself = vp[(size_t)pt * 64 + lane];
  const float* kpb = kp + (size_t)b * (Nc * 64);
  const float* vpb = vp + (size_t)b * (Nc * 64);
  const int* idn = knn + (size_t)pt * Kc;
  float e[40], vv[40];
#pragma unroll
  for (int j = 0; j < 40; ++j) {
    const int ij = idn[j];
    const float kj = kpb[ij * 64 + lane];
    vv[j] = vpb[ij * 64 + lane];
    float p = q * kj;
    p += __shfl_xor(p, 1);
    p += __shfl_xor(p, 2);
    p += __shfl_xor(p, 4);
    p += __shfl_xor(p, 8);
    e[j] = p * 0.25f;  // /sqrt(16)
  }
  float m = e[0];
#pragma unroll
  for (int j = 1; j < 40; ++j) m = fmaxf(m, e[j]);
  float s = 0.f;
#pragma unroll
  for (int j = 0; j < 40; ++j) { e[j] = __expf(e[j] - m); s += e[j]; }
  const float inv = 1.f / s;
  float acc = 0.f;
#pragma unroll
  for (int j = 0; j < 40; ++j) acc = fmaf(e[j] * inv, vv[j], acc);
  const size_t xi = (size_t)b * CN + (size_t)lane * Nc + nn;
  y[xi] = x[xi] + (acc - vself);
}

// ---------------------------------------------------------------- BN stats
// one block per channel; out[c]=mean, out[64+c]=invstd
__global__ __launch_bounds__(256) void stats_kernel(const float* __restrict__ src,
                                                    float* __restrict__ out) {
  const int c = blockIdx.x;
  float s = 0.f, s2 = 0.f;
  for (int b = 0; b < Bc; ++b) {
    const float* p = src + (size_t)b * CN + (size_t)c * Nc;
    for (int i = threadIdx.x; i < Nc; i += 256) {
      const float v = p[i];
      s += v;
      s2 = fmaf(v, v, s2);
    }
  }
  __shared__ float rs[256], rs2[256];
  rs[threadIdx.x] = s; rs2[threadIdx.x] = s2;
  __syncthreads();
  for (int st = 128; st > 0; st >>= 1) {
    if (threadIdx.x < st) {
      rs[threadIdx.x] += rs[threadIdx.x + st];
      rs2[threadIdx.x] += rs2[threadIdx.x + st];
    }
    __syncthreads();
  }
  if (threadIdx.x == 0) {
    const float mean = rs[0] * (1.f / 32768.f);
    const float var = rs2[0] * (1.f / 32768.f) - mean * mean;
    out[c] = mean;
    out[64 + c] = 1.f / sqrtf(var + 1e-5f);
  }
}

// ---------------------------------------------------------------- W2 transpose
__global__ __launch_bounds__(256) void w2t_kernel(const float* __restrict__ W2,
                                                  float* __restrict__ W2t) {
  const int e = blockIdx.x * 256 + threadIdx.x;  // 16384
  const int o = e >> 6, c = e & 63;
  W2t[e] = W2[c * 256 + o];  // W2t[o][c]
}

// ---------------------------------------------------------------- FFN fused
// x1 = BN1(y); z = x1 + W2t^T(leaky(W1 x1))
__global__ __launch_bounds__(256) void ffn_kernel(
    const float* __restrict__ y, const float* __restrict__ W1,
    const float* __restrict__ W2t, const float* __restrict__ st1,
    const float* __restrict__ g1, const float* __restrict__ b1,
    float* __restrict__ z) {
  const int pt = blockIdx.x * 256 + threadIdx.x;  // 0..32767
  const int b = pt >> 13, nn = pt & 8191;
  const float* yb = y + (size_t)b * CN + nn;
  float x1[64], z0[64];
#pragma unroll
  for (int c = 0; c < 64; ++c) {
    const float sc = st1[64 + c] * g1[c];
    x1[c] = (yb[(size_t)c * Nc] - st1[c]) * sc + b1[c];
    z0[c] = x1[c];
  }
  for (int o = 0; o < 256; ++o) {
    const float* w1r = W1 + o * 64;
    float hv = 0.f;
#pragma unroll
    for (int c = 0; c < 64; ++c) hv = fmaf(w1r[c], x1[c], hv);
    hv = hv >= 0.f ? hv : 0.2f * hv;
    const float* w2r = W2t + o * 64;
#pragma unroll
    for (int c = 0; c < 64; ++c) z0[c] = fmaf(w2r[c], hv, z0[c]);
  }
  float* zb = z + (size_t)b * CN + nn;
#pragma unroll
  for (int c = 0; c < 64; ++c) zb[(size_t)c * Nc] = z0[c];
}

// ---------------------------------------------------------------- BN apply
__global__ __launch_bounds__(256) void bn_apply_kernel(
    const float* __restrict__ z, const float* __restrict__ st2,
    const float* __restrict__ g2, const float* __restrict__ b2,
    float* __restrict__ out) {
  const int e = blockIdx.x * 256 + threadIdx.x;  // 2097152
  const int c = (e >> 13) & 63;
  const float sc = st2[64 + c] * g2[c];
  out[e] = (z[e] - st2[c]) * sc + b2[c];
}

// ---------------------------------------------------------------- launch
extern "C" void kernel_launch(void* const* d_in, const int* in_sizes, int n_in,
                              void* d_out, int out_size, void* d_ws, size_t ws_size,
                              hipStream_t stream) {
  (void)in_sizes; (void)n_in; (void)out_size; (void)ws_size;
  const float* x  = (const float*)d_in[0];
  const float* Wq = (const float*)d_in[1];
  const float* Wk = (const float*)d_in[2];
  const float* Wv = (const float*)d_in[3];
  const float* W1 = (const float*)d_in[4];
  const float* W2 = (const float*)d_in[5];
  const float* g1 = (const float*)d_in[6];
  const float* b1 = (const float*)d_in[7];
  const float* g2 = (const float*)d_in[8];
  const float* b2 = (const float*)d_in[9];
  float* out = (float*)d_out;

  float* ws = (float*)d_ws;
  float* aa  = ws;                 // 32768
  float* qp  = aa + 32768;         // 2097152
  float* kp  = qp + 2097152;       // 2097152
  float* vp  = kp + 2097152;       // 2097152
  float* y   = vp + 2097152;       // 2097152
  float* z   = y + 2097152;        // 2097152
  float* st1 = z + 2097152;        // 128
  float* st2 = st1 + 128;          // 128
  float* W2t = st2 + 128;          // 16384
  int* knn   = (int*)(W2t + 16384);// 1310720 ints

  hipLaunchKernelGGL(aa_kernel, dim3(128), dim3(256), 0, stream, x, aa);
  hipLaunchKernelGGL(proj_kernel, dim3(512), dim3(256), 0, stream, x, Wq, Wk, Wv, qp, kp, vp);
  hipLaunchKernelGGL(knn_kernel, dim3(512), dim3(256), 0, stream, x, aa, knn);
  hipLaunchKernelGGL(attn_kernel, dim3(8192), dim3(256), 0, stream, x, qp, kp, vp, knn, y);
  hipLaunchKernelGGL(stats_kernel, dim3(64), dim3(256), 0, stream, y, st1);
  hipLaunchKernelGGL(w2t_kernel, dim3(64), dim3(256), 0, stream, W2, W2t);
  hipLaunchKernelGGL(ffn_kernel, dim3(128), dim3(256), 0, stream, y, W1, W2t, st1, g1, b1, z);
  hipLaunchKernelGGL(stats_kernel, dim3(64), dim3(256), 0, stream, z, st2);
  hipLaunchKernelGGL(bn_apply_kernel, dim3(8192), dim3(256), 0, stream, z, st2, g2, b2, out);
}